// Round 6
// baseline (57466.516 us; speedup 1.0000x reference)
//
#include <hip/hip_runtime.h>
#include <math.h>

#define Hh   512
#define TH   1536
#define LINN 128
#define RD   64          /* ring depth (slots) */
#define L0WG 32          /* layer-0 WGs: 16 h each (4 waves x 2 halves x 2 h) */
#define L1WG 64          /* layer-1 WGs:  8 h each (4 waves x 2 halves x 1 h) */
#define NWG  (L0WG + L1WG)
typedef unsigned long long ull;
typedef unsigned int u32;

#define WS_A     0
#define WS_CC    6144
#define WS_RING0 16384
#define WS_RING1 (WS_RING0 + Hh * RD * 8)
// ws usage ends at 16384 + 2*Hh*RD*8 = 540672 bytes

__device__ __forceinline__ float sigm(float v) { return 1.f / (1.f + __expf(-v)); }
__device__ __forceinline__ float tanh_fast(float x) { return 2.f / (1.f + __expf(-2.f * x)) - 1.f; }
__device__ __forceinline__ ull  pk(float v, u32 tag) { return ((ull)tag << 32) | (ull)__float_as_uint(v); }
__device__ __forceinline__ ull  ring_ld(const ull* p) {
    return __hip_atomic_load(p, __ATOMIC_RELAXED, __HIP_MEMORY_SCOPE_AGENT);
}
__device__ __forceinline__ void ring_st(ull* p, ull v) {
    __hip_atomic_store(p, v, __ATOMIC_RELAXED, __HIP_MEMORY_SCOPE_AGENT);
}

// ---------------------------------------------------------------- prep:
// A[row] = W_ih0[row,:]@W_proc ; CC[row] = W_ih0[row,:]@b_proc + b_ih0 (+ b_hh0 for r,z rows)
__global__ void prep(const float* __restrict__ Wih0, const float* __restrict__ Wproc,
                     const float* __restrict__ bproc, const float* __restrict__ bih0,
                     const float* __restrict__ bhh0, float* __restrict__ A,
                     float* __restrict__ CC)
{
    int row = blockIdx.x * 256 + threadIdx.x;
    if (row >= TH) return;
    const float* w = Wih0 + (size_t)row * LINN;
    float a = 0.f, c = 0.f;
    for (int k = 0; k < LINN; ++k) { float wv = w[k]; a = fmaf(wv, Wproc[k], a); c = fmaf(wv, bproc[k], c); }
    c += bih0[row];
    if (row < 2 * Hh) c += bhh0[row];
    A[row] = a; CC[row] = c;
}

// ---------------------------------------------------------------- ring init (tags + initial state, every call)
__global__ void ringinit(const float* __restrict__ mem, ull* __restrict__ ring0,
                         ull* __restrict__ ring1)
{
    const int t = threadIdx.x;          // 512 threads
    for (int slot = 0; slot < RD; ++slot) {
        ring0[slot * Hh + t] = pk(slot == RD - 1 ? mem[t]      : 0.f, 0u);
        ring1[slot * Hh + t] = pk(slot == RD - 1 ? mem[Hh + t] : 0.f, 0u);
    }
}

// ---------------------------------------------------------------- fused register-dataflow scan
// No LDS, no barriers. Each HALF-WAVE (32 lanes) is an independent agent:
//   L0 half: 2 h-rows (6 gate rows), 96 weight floats in VGPRs, k-slice = {4*s32+128c+d}
//   L1 half: 1 h-row  (3 ih + 3 hh rows), 96 weight floats in VGPRs
// Per step: batch-issue all ring polls (1 LLC RTT), per-word verify, FMA from
// registers, 5-round shfl reduce within the half, lane s32==0 stores tagged h.
__launch_bounds__(256, 1)
__global__ void fused(const float* __restrict__ input, const float* __restrict__ resid,
                      const float* __restrict__ Whh0, const float* __restrict__ bhh0,
                      const float* __restrict__ A, const float* __restrict__ CC,
                      const float* __restrict__ Wih1, const float* __restrict__ Whh1,
                      const float* __restrict__ bih1, const float* __restrict__ bhh1,
                      ull* __restrict__ ring0, ull* __restrict__ ring1,
                      float* __restrict__ outp, int T)
{
    const int tid  = threadIdx.x;
    const int wg   = blockIdx.x;
    const int lane = tid & 63;
    const int wv   = tid >> 6;          // wave 0..3
    const int s32  = lane & 31;         // k-lane within half
    const int ph   = lane >> 5;         // half 0/1

    if (wg < L0WG) {
        // ================= layer 0: half owns h {jb, jb+1} =================
        const int jb = wg * 16 + wv * 4 + ph * 2;
        float4 W[2][3][4];
#pragma unroll
        for (int m = 0; m < 2; ++m)
#pragma unroll
            for (int g = 0; g < 3; ++g)
#pragma unroll
                for (int c = 0; c < 4; ++c)
                    W[m][g][c] = *(const float4*)&Whh0[(size_t)(g * Hh + jb + m) * Hh + 4 * s32 + 128 * c];
        float Ar[2], Az[2], An[2], Cr[2], Cz[2], Cn[2], Bn[2];
#pragma unroll
        for (int m = 0; m < 2; ++m) {
            const int j = jb + m;
            Ar[m] = A[j]; Az[m] = A[j + Hh]; An[m] = A[j + 2 * Hh];
            Cr[m] = CC[j]; Cz[m] = CC[j + Hh]; Cn[m] = CC[j + 2 * Hh];
            Bn[m] = bhh0[j + 2 * Hh];
        }

        for (int s = 0; s < T; ++s) {
            // amortized back-pressure: every 32 steps require all L1 halves past s-32
            if ((s & 31) == 0 && s >= 32) {
                const ull* bp = ring1 + (size_t)((s - 32) & (RD - 1)) * Hh;
                const u32 need = (u32)(s - 31);
                ull b[8];
#pragma unroll
                for (int m = 0; m < 8; ++m) b[m] = ring_ld(bp + lane * 8 + m);
#pragma unroll
                for (int m = 0; m < 8; ++m)
                    while ((u32)(b[m] >> 32) < need) b[m] = ring_ld(bp + lane * 8 + m);
            }
            const float x = input[s];
            const ull* p0 = ring0 + (size_t)((s - 1) & (RD - 1)) * Hh;
            const u32 tgt = (u32)s;
            ull v[16];
#pragma unroll
            for (int c = 0; c < 4; ++c)
#pragma unroll
                for (int d = 0; d < 4; ++d)
                    v[c * 4 + d] = ring_ld(p0 + 4 * s32 + 128 * c + d);
            ull vs0 = ring_ld(p0 + jb);
            ull vs1 = ring_ld(p0 + jb + 1);
#pragma unroll
            for (int i = 0; i < 16; ++i) {
                const int c = i >> 2, d = i & 3;
                while ((u32)(v[i] >> 32) < tgt) v[i] = ring_ld(p0 + 4 * s32 + 128 * c + d);
            }
            while ((u32)(vs0 >> 32) < tgt) vs0 = ring_ld(p0 + jb);
            while ((u32)(vs1 >> 32) < tgt) vs1 = ring_ld(p0 + jb + 1);
            float h[16];
#pragma unroll
            for (int i = 0; i < 16; ++i) h[i] = __uint_as_float((u32)v[i]);
            const float hp[2] = { __uint_as_float((u32)vs0), __uint_as_float((u32)vs1) };

            float acc[2][3];
#pragma unroll
            for (int m = 0; m < 2; ++m)
#pragma unroll
                for (int g = 0; g < 3; ++g) {
                    float a = 0.f;
#pragma unroll
                    for (int c = 0; c < 4; ++c) {
                        const float4 w = W[m][g][c];
                        a = fmaf(w.x, h[4 * c + 0], a); a = fmaf(w.y, h[4 * c + 1], a);
                        a = fmaf(w.z, h[4 * c + 2], a); a = fmaf(w.w, h[4 * c + 3], a);
                    }
                    acc[m][g] = a;
                }
#pragma unroll
            for (int off = 16; off > 0; off >>= 1)
#pragma unroll
                for (int m = 0; m < 2; ++m)
#pragma unroll
                    for (int g = 0; g < 3; ++g)
                        acc[m][g] += __shfl_xor(acc[m][g], off);
            if (s32 == 0) {
#pragma unroll
                for (int m = 0; m < 2; ++m) {
                    const float r  = sigm(fmaf(Ar[m], x, Cr[m]) + acc[m][0]);
                    const float z  = sigm(fmaf(Az[m], x, Cz[m]) + acc[m][1]);
                    const float n  = tanh_fast(fmaf(An[m], x, Cn[m]) + r * (acc[m][2] + Bn[m]));
                    const float hn = (1.f - z) * n + z * hp[m];
                    ring_st(ring0 + (size_t)(s & (RD - 1)) * Hh + jb + m, pk(hn, (u32)(s + 1)));
                    if (s == T - 1) outp[Hh + jb + m] = hn;
                }
            }
        }
    } else {
        // ================= layer 1 (lag 1): half owns h {j} =================
        const int wg1 = wg - L0WG;
        const int j   = wg1 * 8 + wv * 2 + ph;
        float4 Wi[3][4], Wh[3][4];
#pragma unroll
        for (int g = 0; g < 3; ++g)
#pragma unroll
            for (int c = 0; c < 4; ++c) {
                const size_t ro = (size_t)(g * Hh + j) * Hh + 4 * s32 + 128 * c;
                Wi[g][c] = *(const float4*)&Wih1[ro];
                Wh[g][c] = *(const float4*)&Whh1[ro];
            }
        const float Br  = bih1[j] + bhh1[j];
        const float Bz  = bih1[j + Hh] + bhh1[j + Hh];
        const float Bin = bih1[j + 2 * Hh];
        const float Bhn = bhh1[j + 2 * Hh];
        float res = resid[j];

        for (int u = 0; u < T; ++u) {
            const ull* a0 = ring0 + (size_t)(u & (RD - 1)) * Hh;        // h0[u], tag u+1
            const ull* a1 = ring1 + (size_t)((u - 1) & (RD - 1)) * Hh;  // h1[u-1], tag u
            const u32 t0 = (u32)(u + 1), t1 = (u32)u;
            ull v0[16], v1[16];
#pragma unroll
            for (int c = 0; c < 4; ++c)
#pragma unroll
                for (int d = 0; d < 4; ++d) {
                    v0[c * 4 + d] = ring_ld(a0 + 4 * s32 + 128 * c + d);
                    v1[c * 4 + d] = ring_ld(a1 + 4 * s32 + 128 * c + d);
                }
            ull vself = ring_ld(a1 + j);
#pragma unroll
            for (int i = 0; i < 16; ++i) {
                const int c = i >> 2, d = i & 3;
                while ((u32)(v0[i] >> 32) < t0) v0[i] = ring_ld(a0 + 4 * s32 + 128 * c + d);
                while ((u32)(v1[i] >> 32) < t1) v1[i] = ring_ld(a1 + 4 * s32 + 128 * c + d);
            }
            while ((u32)(vself >> 32) < t1) vself = ring_ld(a1 + j);
            float h0[16], h1[16];
#pragma unroll
            for (int i = 0; i < 16; ++i) {
                h0[i] = __uint_as_float((u32)v0[i]);
                h1[i] = __uint_as_float((u32)v1[i]);
            }
            const float hp = __uint_as_float((u32)vself);

            float ai[3], ah[3];
#pragma unroll
            for (int g = 0; g < 3; ++g) {
                float s1 = 0.f, s2 = 0.f;
#pragma unroll
                for (int c = 0; c < 4; ++c) {
                    const float4 wi = Wi[g][c], wh = Wh[g][c];
                    s1 = fmaf(wi.x, h0[4 * c + 0], s1); s1 = fmaf(wi.y, h0[4 * c + 1], s1);
                    s1 = fmaf(wi.z, h0[4 * c + 2], s1); s1 = fmaf(wi.w, h0[4 * c + 3], s1);
                    s2 = fmaf(wh.x, h1[4 * c + 0], s2); s2 = fmaf(wh.y, h1[4 * c + 1], s2);
                    s2 = fmaf(wh.z, h1[4 * c + 2], s2); s2 = fmaf(wh.w, h1[4 * c + 3], s2);
                }
                ai[g] = s1; ah[g] = s2;
            }
#pragma unroll
            for (int off = 16; off > 0; off >>= 1)
#pragma unroll
                for (int g = 0; g < 3; ++g) {
                    ai[g] += __shfl_xor(ai[g], off);
                    ah[g] += __shfl_xor(ah[g], off);
                }
            if (s32 == 0) {
                const float r   = sigm(ai[0] + ah[0] + Br);
                const float z   = sigm(ai[1] + ah[1] + Bz);
                const float n   = tanh_fast(ai[2] + Bin + r * (ah[2] + Bhn));
                const float h1n = (1.f - z) * n + z * hp;
                ring_st(ring1 + (size_t)(u & (RD - 1)) * Hh + j, pk(h1n, (u32)(u + 1)));
                res = sigm(res + h1n);
                if (u == T - 1) { outp[j] = res; outp[2 * Hh + j] = h1n; }
            }
        }
    }
}

// ---------------------------------------------------------------- host
extern "C" void kernel_launch(void* const* d_in, const int* in_sizes, int n_in,
                              void* d_out, int out_size, void* d_ws, size_t ws_size,
                              hipStream_t stream)
{
    const float* input    = (const float*)d_in[0];
    const float* residual = (const float*)d_in[1];
    const float* memory   = (const float*)d_in[2];
    const float* Wproc    = (const float*)d_in[3];
    const float* bproc    = (const float*)d_in[4];
    const float* Wih0     = (const float*)d_in[5];
    const float* Whh0     = (const float*)d_in[6];
    const float* bih0     = (const float*)d_in[7];
    const float* bhh0     = (const float*)d_in[8];
    const float* Wih1     = (const float*)d_in[9];
    const float* Whh1     = (const float*)d_in[10];
    const float* bih1     = (const float*)d_in[11];
    const float* bhh1     = (const float*)d_in[12];
    const int L = in_sizes[0];
    const int T = L - 1;
    float* out = (float*)d_out;
    char* ws = (char*)d_ws;

    float* A     = (float*)(ws + WS_A);
    float* CC    = (float*)(ws + WS_CC);
    ull*   ring0 = (ull*)(ws + WS_RING0);
    ull*   ring1 = (ull*)(ws + WS_RING1);

    prep<<<dim3((TH + 255) / 256), dim3(256), 0, stream>>>(Wih0, Wproc, bproc, bih0, bhh0, A, CC);
    ringinit<<<dim3(1), dim3(512), 0, stream>>>(memory, ring0, ring1);
    fused<<<dim3(NWG), dim3(256), 0, stream>>>(input, residual, Whh0, bhh0, A, CC,
                                               Wih1, Whh1, bih1, bhh1,
                                               ring0, ring1, out, T);
}

// Round 7
// 26226.254 us; speedup vs baseline: 2.1912x; 2.1912x over previous
//
#include <hip/hip_runtime.h>
#include <math.h>

#define Hh   512
#define TH   1536
#define LINN 128
#define RD   32          /* ring depth (slots) */
#define NWG0 64          /* layer-0 WGs: 8 h each */
#define NWG1 128         /* layer-1 WGs: 4 h each */
#define NWG  (NWG0 + NWG1)
typedef unsigned long long ull;
typedef unsigned int u32;

#define WS_A     0
#define WS_CC    6144
#define WS_RING0 16384
#define WS_RING1 (WS_RING0 + Hh * RD * 8)
// ws usage ends at 16384 + 2*Hh*RD*8 = 278528 bytes

__device__ __forceinline__ float sigm(float v) { return 1.f / (1.f + __expf(-v)); }
__device__ __forceinline__ float tanh_fast(float x) { return 2.f / (1.f + __expf(-2.f * x)) - 1.f; }
__device__ __forceinline__ ull  pk(float v, u32 tag) { return ((ull)tag << 32) | (ull)__float_as_uint(v); }
__device__ __forceinline__ ull  ring_ld(const ull* p) {
    return __hip_atomic_load(p, __ATOMIC_RELAXED, __HIP_MEMORY_SCOPE_AGENT);
}
__device__ __forceinline__ void ring_st(ull* p, ull v) {
    __hip_atomic_store(p, v, __ATOMIC_RELAXED, __HIP_MEMORY_SCOPE_AGENT);
}

// ---------------------------------------------------------------- prep:
// A[row] = W_ih0[row,:]@W_proc ; CC[row] = W_ih0[row,:]@b_proc + b_ih0 (+ b_hh0 for r,z rows)
__global__ void prep(const float* __restrict__ Wih0, const float* __restrict__ Wproc,
                     const float* __restrict__ bproc, const float* __restrict__ bih0,
                     const float* __restrict__ bhh0, float* __restrict__ A,
                     float* __restrict__ CC)
{
    int row = blockIdx.x * 256 + threadIdx.x;
    if (row >= TH) return;
    const float* w = Wih0 + (size_t)row * LINN;
    float a = 0.f, c = 0.f;
    for (int k = 0; k < LINN; ++k) { float wv = w[k]; a = fmaf(wv, Wproc[k], a); c = fmaf(wv, bproc[k], c); }
    c += bih0[row];
    if (row < 2 * Hh) c += bhh0[row];
    A[row] = a; CC[row] = c;
}

// ---------------------------------------------------------------- ring init (tags + initial state, every call)
__global__ void ringinit(const float* __restrict__ mem, ull* __restrict__ ring0,
                         ull* __restrict__ ring1)
{
    const int t = threadIdx.x;          // 512 threads
    for (int slot = 0; slot < RD; ++slot) {
        ring0[slot * Hh + t] = pk(slot == RD - 1 ? mem[t]      : 0.f, 0u);
        ring1[slot * Hh + t] = pk(slot == RD - 1 ? mem[Hh + t] : 0.f, 0u);
    }
}

// ---------------------------------------------------------------- fused self-timed dataflow scan
// R3 structure: WG 0..63 layer 0 (8 h each), WG 64..191 layer 1 lag-1 (4 h each).
// Weights in LDS, h broadcast in double-buffered LDS (1 barrier/step).
// LDS reads via float4 chunks idx = lane + 32c (conflict-free b128).
// Ring polls: all words issued concurrently, per-word spin, no sleep.
__launch_bounds__(256, 1)
__global__ void fused(const float* __restrict__ input, const float* __restrict__ resid,
                      const float* __restrict__ Whh0, const float* __restrict__ bhh0,
                      const float* __restrict__ A, const float* __restrict__ CC,
                      const float* __restrict__ Wih1, const float* __restrict__ Whh1,
                      const float* __restrict__ bih1, const float* __restrict__ bhh1,
                      ull* __restrict__ ring0, ull* __restrict__ ring1,
                      float* __restrict__ outp, int T)
{
    __shared__ __align__(16) float smem[14336];   // 56 KB max (L1 path)
    const int tid = threadIdx.x;
    const int wg  = blockIdx.x;

    if (wg < NWG0) {
        // ================= layer 0: 8 h per WG =================
        float* Wl = smem;                    // [24][512]
        float* hl = smem + 12288;            // [2][512]
        const int jl = tid >> 5;             // h-subindex 0..7
        const int s2 = tid & 31;             // k-lane
        const int jg = wg * 8 + jl;
        for (int i = tid; i < 24 * Hh; i += 256) {
            int lr = i >> 9, k = i & (Hh - 1);
            int g = lr % 3, j = lr / 3;
            Wl[i] = Whh0[(size_t)(g * Hh + wg * 8 + j) * Hh + k];
        }
        const float Ar = A[jg], Az = A[jg + Hh], An = A[jg + 2 * Hh];
        const float Cr = CC[jg], Cz = CC[jg + Hh], Cn = CC[jg + 2 * Hh];
        const float Bn = bhh0[jg + 2 * Hh];
        const float4* W4 = (const float4*)Wl;    // row r -> float4 base r*128
        __syncthreads();

        for (int s = 0; s < T; ++s) {
            const float x = input[s];                        // independent, issued early
            const ull* prev = ring0 + (size_t)((s - 1) & (RD - 1)) * Hh;
            const u32 tgt = (u32)s;
            ull p0 = ring_ld(prev + tid);                    // both loads in flight
            ull p1 = ring_ld(prev + tid + 256);
            while ((u32)(p0 >> 32) < tgt) p0 = ring_ld(prev + tid);
            while ((u32)(p1 >> 32) < tgt) p1 = ring_ld(prev + tid + 256);
            if (tid == 0 && s >= 16 && (s & 15) == 0) {      // amortized back-pressure (1 word)
                const ull* bp = ring1 + (size_t)((s - 16) & (RD - 1)) * Hh;
                while ((u32)(ring_ld(bp) >> 32) < (u32)(s - 15)) {}
            }
            float* hbc = hl + (s & 1) * Hh;
            hbc[tid]       = __uint_as_float((u32)p0);
            hbc[tid + 256] = __uint_as_float((u32)p1);
            __syncthreads();                 // single barrier (double-buffered broadcast)
            const float4* hb4 = (const float4*)hbc;
            float4 hv[4];
#pragma unroll
            for (int c = 0; c < 4; ++c) hv[c] = hb4[s2 + 32 * c];
            float acc[3];
#pragma unroll
            for (int g = 0; g < 3; ++g) {
                const float4* Wr = W4 + (jl * 3 + g) * 128;
                float a = 0.f;
#pragma unroll
                for (int c = 0; c < 4; ++c) {
                    const float4 w = Wr[s2 + 32 * c], h = hv[c];
                    a = fmaf(w.x, h.x, a); a = fmaf(w.y, h.y, a);
                    a = fmaf(w.z, h.z, a); a = fmaf(w.w, h.w, a);
                }
                acc[g] = a;
            }
#pragma unroll
            for (int off = 16; off > 0; off >>= 1)
#pragma unroll
                for (int g = 0; g < 3; ++g)
                    acc[g] += __shfl_xor(acc[g], off);
            if (s2 == 0) {
                const float r  = sigm(fmaf(Ar, x, Cr) + acc[0]);
                const float z  = sigm(fmaf(Az, x, Cz) + acc[1]);
                const float n  = tanh_fast(fmaf(An, x, Cn) + r * (acc[2] + Bn));
                const float hn = (1.f - z) * n + z * hbc[jg];
                ring_st(ring0 + (size_t)(s & (RD - 1)) * Hh + jg, pk(hn, (u32)(s + 1)));
                if (s == T - 1) outp[Hh + jg] = hn;
            }
        }
    } else {
        // ================= layer 1 (lag 1): 4 h per WG =================
        float* Wl  = smem;                   // [24][512]: per h: ihR,ihZ,ihN,hhR,hhZ,hhN
        float* hl0 = smem + 12288;           // [2][512]
        float* hl1 = smem + 13312;           // [2][512]
        const int w  = tid >> 6;             // wave 0..3 -> h-subindex
        const int l  = tid & 63;
        const int jg = (wg - NWG0) * 4 + w;
        for (int i = tid; i < 24 * Hh; i += 256) {
            int lr = i >> 9, k = i & (Hh - 1);
            int ww = lr / 6, qq = lr % 6;
            int hj = (wg - NWG0) * 4 + ww;
            const float* src = (qq < 3) ? &Wih1[(size_t)(qq * Hh + hj) * Hh]
                                        : &Whh1[(size_t)((qq - 3) * Hh + hj) * Hh];
            Wl[i] = src[k];
        }
        const float Br  = bih1[jg] + bhh1[jg];
        const float Bz  = bih1[jg + Hh] + bhh1[jg + Hh];
        const float Bin = bih1[jg + 2 * Hh];
        const float Bhn = bhh1[jg + 2 * Hh];
        const float4* W4 = (const float4*)Wl;
        float res = resid[jg];               // live in lane 0 of each wave
        __syncthreads();

        for (int u = 0; u < T; ++u) {
            const ull* b0 = ring0 + (size_t)(u & (RD - 1)) * Hh;        // h0[u],   tag u+1
            const ull* b1 = ring1 + (size_t)((u - 1) & (RD - 1)) * Hh;  // h1[u-1], tag u
            const u32 t0g = (u32)(u + 1), t1g = (u32)u;
            ull a0 = ring_ld(b0 + tid);                  // all four loads in flight
            ull a1 = ring_ld(b0 + tid + 256);
            ull c0 = ring_ld(b1 + tid);
            ull c1 = ring_ld(b1 + tid + 256);
            while ((u32)(c0 >> 32) < t1g) c0 = ring_ld(b1 + tid);
            while ((u32)(c1 >> 32) < t1g) c1 = ring_ld(b1 + tid + 256);
            while ((u32)(a0 >> 32) < t0g) a0 = ring_ld(b0 + tid);
            while ((u32)(a1 >> 32) < t0g) a1 = ring_ld(b0 + tid + 256);
            float* hc0 = hl0 + (u & 1) * Hh;
            float* hc1 = hl1 + (u & 1) * Hh;
            hc0[tid]       = __uint_as_float((u32)a0);
            hc0[tid + 256] = __uint_as_float((u32)a1);
            hc1[tid]       = __uint_as_float((u32)c0);
            hc1[tid + 256] = __uint_as_float((u32)c1);
            __syncthreads();                 // single barrier
            const float4* h04 = (const float4*)hc0;
            const float4* h14 = (const float4*)hc1;
            float4 x0[2], x1[2];
#pragma unroll
            for (int c = 0; c < 2; ++c) { x0[c] = h04[l + 64 * c]; x1[c] = h14[l + 64 * c]; }
            float ai[3], ah[3];
#pragma unroll
            for (int g = 0; g < 3; ++g) {
                const float4* Wi = W4 + (w * 6 + g) * 128;
                const float4* Wh = W4 + (w * 6 + 3 + g) * 128;
                float s1 = 0.f, s2v = 0.f;
#pragma unroll
                for (int c = 0; c < 2; ++c) {
                    const float4 wi = Wi[l + 64 * c], wh = Wh[l + 64 * c];
                    s1  = fmaf(wi.x, x0[c].x, s1);  s1  = fmaf(wi.y, x0[c].y, s1);
                    s1  = fmaf(wi.z, x0[c].z, s1);  s1  = fmaf(wi.w, x0[c].w, s1);
                    s2v = fmaf(wh.x, x1[c].x, s2v); s2v = fmaf(wh.y, x1[c].y, s2v);
                    s2v = fmaf(wh.z, x1[c].z, s2v); s2v = fmaf(wh.w, x1[c].w, s2v);
                }
                ai[g] = s1; ah[g] = s2v;
            }
#pragma unroll
            for (int off = 32; off > 0; off >>= 1)
#pragma unroll
                for (int g = 0; g < 3; ++g) {
                    ai[g] += __shfl_xor(ai[g], off);
                    ah[g] += __shfl_xor(ah[g], off);
                }
            if (l == 0) {
                const float r   = sigm(ai[0] + ah[0] + Br);
                const float z   = sigm(ai[1] + ah[1] + Bz);
                const float n   = tanh_fast(ai[2] + Bin + r * (ah[2] + Bhn));
                const float h1n = (1.f - z) * n + z * hc1[jg];
                ring_st(ring1 + (size_t)(u & (RD - 1)) * Hh + jg, pk(h1n, (u32)(u + 1)));
                res = sigm(res + h1n);
                if (u == T - 1) { outp[jg] = res; outp[2 * Hh + jg] = h1n; }
            }
        }
    }
}

// ---------------------------------------------------------------- host
extern "C" void kernel_launch(void* const* d_in, const int* in_sizes, int n_in,
                              void* d_out, int out_size, void* d_ws, size_t ws_size,
                              hipStream_t stream)
{
    const float* input    = (const float*)d_in[0];
    const float* residual = (const float*)d_in[1];
    const float* memory   = (const float*)d_in[2];
    const float* Wproc    = (const float*)d_in[3];
    const float* bproc    = (const float*)d_in[4];
    const float* Wih0     = (const float*)d_in[5];
    const float* Whh0     = (const float*)d_in[6];
    const float* bih0     = (const float*)d_in[7];
    const float* bhh0     = (const float*)d_in[8];
    const float* Wih1     = (const float*)d_in[9];
    const float* Whh1     = (const float*)d_in[10];
    const float* bih1     = (const float*)d_in[11];
    const float* bhh1     = (const float*)d_in[12];
    const int L = in_sizes[0];
    const int T = L - 1;
    float* out = (float*)d_out;
    char* ws = (char*)d_ws;

    float* A     = (float*)(ws + WS_A);
    float* CC    = (float*)(ws + WS_CC);
    ull*   ring0 = (ull*)(ws + WS_RING0);
    ull*   ring1 = (ull*)(ws + WS_RING1);

    prep<<<dim3((TH + 255) / 256), dim3(256), 0, stream>>>(Wih0, Wproc, bproc, bih0, bhh0, A, CC);
    ringinit<<<dim3(1), dim3(512), 0, stream>>>(memory, ring0, ring1);
    fused<<<dim3(NWG), dim3(256), 0, stream>>>(input, residual, Whh0, bhh0, A, CC,
                                               Wih1, Whh1, bih1, bhh1,
                                               ring0, ring1, out, T);
}

// Round 8
// 18754.037 us; speedup vs baseline: 3.0642x; 1.3984x over previous
//
#include <hip/hip_runtime.h>
#include <math.h>

#define Hh   512
#define TH   1536
#define LINN 128
typedef unsigned long long ull;
typedef unsigned int u32;

#define WS_A     0
#define WS_CC    6144
#define WS_RING0 16384
#define WS_RING1 49152
// ws usage ends at 81920 bytes

__device__ __forceinline__ float sigm(float v) { return 1.f / (1.f + __expf(-v)); }
__device__ __forceinline__ float tanh_fast(float x) { return 2.f / (1.f + __expf(-2.f * x)) - 1.f; }
__device__ __forceinline__ ull  pk(float v, u32 tag) { return ((ull)tag << 32) | (ull)__float_as_uint(v); }
__device__ __forceinline__ ull  ring_ld(const ull* p) {
    return __hip_atomic_load(p, __ATOMIC_RELAXED, __HIP_MEMORY_SCOPE_AGENT);
}
__device__ __forceinline__ void ring_st(ull* p, ull v) {
    __hip_atomic_store(p, v, __ATOMIC_RELAXED, __HIP_MEMORY_SCOPE_AGENT);
}

// Spin with capped backoff: probes 1-2 run hot (no added latency on the exit
// path); from the 3rd reload onward, sleep ~128cyc before each retry to cap
// the LLC read-storm (the metastable slow mode seen in R3/R7 rocprof).
#define SPIN_LD(var, ptr, tag)                                        \
    {                                                                 \
        int _t = 0;                                                   \
        var = ring_ld(ptr);                                           \
        while ((u32)((var) >> 32) < (tag)) {                          \
            if (++_t > 2) __builtin_amdgcn_s_sleep(2);                \
            var = ring_ld(ptr);                                       \
        }                                                             \
    }

// ---------------------------------------------------------------- prep:
// A[row] = W_ih0[row,:]@W_proc ; CC[row] = W_ih0[row,:]@b_proc + b_ih0 (+ b_hh0 for r,z rows)
__global__ void prep(const float* __restrict__ Wih0, const float* __restrict__ Wproc,
                     const float* __restrict__ bproc, const float* __restrict__ bih0,
                     const float* __restrict__ bhh0, float* __restrict__ A,
                     float* __restrict__ CC)
{
    int row = blockIdx.x * 256 + threadIdx.x;
    if (row >= TH) return;
    const float* w = Wih0 + (size_t)row * LINN;
    float a = 0.f, c = 0.f;
    for (int k = 0; k < LINN; ++k) { float wv = w[k]; a = fmaf(wv, Wproc[k], a); c = fmaf(wv, bproc[k], c); }
    c += bih0[row];
    if (row < 2 * Hh) c += bhh0[row];
    A[row] = a; CC[row] = c;
}

// ---------------------------------------------------------------- ring init (tags + initial state, every call)
__global__ void ringinit(const float* __restrict__ mem, ull* __restrict__ ring0,
                         ull* __restrict__ ring1)
{
    const int t = threadIdx.x;          // 512 threads
    for (int slot = 0; slot < 8; ++slot) {
        ring0[slot * Hh + t] = pk(slot == 7 ? mem[t]      : 0.f, 0u);
        ring1[slot * Hh + t] = pk(slot == 7 ? mem[Hh + t] : 0.f, 0u);
    }
}

// ---------------------------------------------------------------- fused self-timed dataflow scan
// R3-verbatim structure: WG 0..63 layer 0 (8 h each), WG 64..191 layer 1 lag-1
// (4 h each). 8-deep tagged rings, relaxed agent atomics, sequential per-word
// polls, 2-barrier LDS broadcast. Deltas vs R3: capped-backoff spins, float4
// LDS reads (contiguous, conflict-free), back-pressure probe hoisted before
// the data polls (overlaps the looser wait with the tighter one).
__launch_bounds__(256, 1)
__global__ void fused(const float* __restrict__ input, const float* __restrict__ resid,
                      const float* __restrict__ Whh0, const float* __restrict__ bhh0,
                      const float* __restrict__ A, const float* __restrict__ CC,
                      const float* __restrict__ Wih1, const float* __restrict__ Whh1,
                      const float* __restrict__ bih1, const float* __restrict__ bhh1,
                      ull* __restrict__ ring0, ull* __restrict__ ring1,
                      float* __restrict__ outp, int T)
{
    __shared__ __align__(16) float smem[13312];   // 52 KB: 24x512 weights + h buffers
    const int tid = threadIdx.x;
    const int wg  = blockIdx.x;

    if (wg < 64) {
        // ---------------- layer 0 ----------------
        float* Wl = smem;                  // [24][512]
        float* hl = smem + 12288;          // [512]
        const int jl = tid >> 5;           // 0..7   local h-index
        const int s2 = tid & 31;           // k-lane
        const int jg = wg * 8 + jl;
        for (int i = tid; i < 24 * Hh; i += 256) {
            int lr = i >> 9, k = i & (Hh - 1);
            int g = lr % 3, j = lr / 3;
            Wl[i] = Whh0[(size_t)(g * Hh + wg * 8 + j) * Hh + k];
        }
        const float Ar = A[jg], Az = A[jg + Hh], An = A[jg + 2 * Hh];
        const float Cr = CC[jg], Cz = CC[jg + Hh], Cn = CC[jg + 2 * Hh];
        const float Bn = bhh0[jg + 2 * Hh];
        const float4* W4 = (const float4*)Wl;    // row r -> float4 base r*128
        __syncthreads();

        for (int s = 0; s < T; ++s) {
            if (tid == 0 && s >= 7) {            // back-pressure FIRST (looser wait,
                const ull* bp = ring1 + (size_t)((s - 7) & 7) * Hh;   // overlaps data wait)
                ull b;
                SPIN_LD(b, bp, (u32)(s - 6));
            }
            const ull* base = ring0 + (size_t)((s - 1) & 7) * Hh;
            const u32 tgt = (u32)s;
            ull w0, w1;
            SPIN_LD(w0, base + tid, tgt);
            SPIN_LD(w1, base + tid + 256, tgt);
            __syncthreads();                     // all polls done -> safe to overwrite hl
            hl[tid]       = __uint_as_float((u32)w0);
            hl[tid + 256] = __uint_as_float((u32)w1);
            __syncthreads();
            const float x = input[s];
            const float4* hb4 = (const float4*)hl;
            float4 hv[4];
#pragma unroll
            for (int c = 0; c < 4; ++c) hv[c] = hb4[s2 + 32 * c];
            float acc[3];
#pragma unroll
            for (int g = 0; g < 3; ++g) {
                const float4* Wr = W4 + (jl * 3 + g) * 128;
                float a = 0.f;
#pragma unroll
                for (int c = 0; c < 4; ++c) {
                    const float4 w = Wr[s2 + 32 * c], h = hv[c];
                    a = fmaf(w.x, h.x, a); a = fmaf(w.y, h.y, a);
                    a = fmaf(w.z, h.z, a); a = fmaf(w.w, h.w, a);
                }
                acc[g] = a;
            }
#pragma unroll
            for (int o = 16; o > 0; o >>= 1) {
                acc[0] += __shfl_xor(acc[0], o);
                acc[1] += __shfl_xor(acc[1], o);
                acc[2] += __shfl_xor(acc[2], o);
            }
            if (s2 == 0) {
                const float r  = sigm(fmaf(Ar, x, Cr) + acc[0]);
                const float z  = sigm(fmaf(Az, x, Cz) + acc[1]);
                const float n  = tanh_fast(fmaf(An, x, Cn) + r * (acc[2] + Bn));
                const float hn = (1.f - z) * n + z * hl[jg];
                ring_st(ring0 + (size_t)(s & 7) * Hh + jg, pk(hn, (u32)(s + 1)));
                if (s == T - 1) outp[Hh + jg] = hn;
            }
        }
    } else {
        // ---------------- layer 1 (lag 1) ----------------
        float* Wl  = smem;                 // [24][512]: per h: ihR,ihZ,ihN,hhR,hhZ,hhN
        float* hl0 = smem + 12288;         // [512]
        float* hl1 = smem + 12800;         // [512]
        const int w  = tid >> 6;           // wave 0..3 -> h-subindex
        const int l  = tid & 63;
        const int jg = (wg - 64) * 4 + w;
        for (int i = tid; i < 24 * Hh; i += 256) {
            int lr = i >> 9, k = i & (Hh - 1);
            int ww = lr / 6, q = lr % 6;
            int hj = (wg - 64) * 4 + ww;
            const float* src = (q < 3) ? &Wih1[(size_t)(q * Hh + hj) * Hh]
                                       : &Whh1[(size_t)((q - 3) * Hh + hj) * Hh];
            Wl[i] = src[k];
        }
        const float Br  = bih1[jg] + bhh1[jg];
        const float Bz  = bih1[jg + Hh] + bhh1[jg + Hh];
        const float Bin = bih1[jg + 2 * Hh];
        const float Bhn = bhh1[jg + 2 * Hh];
        const float4* W4 = (const float4*)Wl;
        float resl = resid[jg];            // live in lane 0 of each wave
        __syncthreads();

        for (int u = 0; u < T; ++u) {
            const ull* b0 = ring0 + (size_t)(u & 7) * Hh;          // h0[u], tag u+1
            const ull* b1 = ring1 + (size_t)((u - 1) & 7) * Hh;    // h1[u-1], tag u
            const u32 t0g = (u32)(u + 1), t1g = (u32)u;
            ull a0, a1, c0, c1;
            SPIN_LD(a0, b0 + tid, t0g);
            SPIN_LD(a1, b0 + tid + 256, t0g);
            SPIN_LD(c0, b1 + tid, t1g);
            SPIN_LD(c1, b1 + tid + 256, t1g);
            __syncthreads();                 // all polls done -> safe to overwrite hl0/hl1
            hl0[tid]       = __uint_as_float((u32)a0);
            hl0[tid + 256] = __uint_as_float((u32)a1);
            hl1[tid]       = __uint_as_float((u32)c0);
            hl1[tid + 256] = __uint_as_float((u32)c1);
            __syncthreads();
            const float4* h04 = (const float4*)hl0;
            const float4* h14 = (const float4*)hl1;
            float4 x0[2], x1[2];
#pragma unroll
            for (int c = 0; c < 2; ++c) { x0[c] = h04[l + 64 * c]; x1[c] = h14[l + 64 * c]; }
            float ai[3], ah[3];
#pragma unroll
            for (int g = 0; g < 3; ++g) {
                const float4* Wi = W4 + (w * 6 + g) * 128;
                const float4* Wh = W4 + (w * 6 + 3 + g) * 128;
                float s1 = 0.f, s2v = 0.f;
#pragma unroll
                for (int c = 0; c < 2; ++c) {
                    const float4 wi = Wi[l + 64 * c], wh = Wh[l + 64 * c];
                    s1  = fmaf(wi.x, x0[c].x, s1);  s1  = fmaf(wi.y, x0[c].y, s1);
                    s1  = fmaf(wi.z, x0[c].z, s1);  s1  = fmaf(wi.w, x0[c].w, s1);
                    s2v = fmaf(wh.x, x1[c].x, s2v); s2v = fmaf(wh.y, x1[c].y, s2v);
                    s2v = fmaf(wh.z, x1[c].z, s2v); s2v = fmaf(wh.w, x1[c].w, s2v);
                }
                ai[g] = s1; ah[g] = s2v;
            }
#pragma unroll
            for (int o = 32; o > 0; o >>= 1) {
                ai[0] += __shfl_xor(ai[0], o); ai[1] += __shfl_xor(ai[1], o); ai[2] += __shfl_xor(ai[2], o);
                ah[0] += __shfl_xor(ah[0], o); ah[1] += __shfl_xor(ah[1], o); ah[2] += __shfl_xor(ah[2], o);
            }
            if (l == 0) {
                const float r   = sigm(ai[0] + ah[0] + Br);
                const float z   = sigm(ai[1] + ah[1] + Bz);
                const float n   = tanh_fast(ai[2] + Bin + r * (ah[2] + Bhn));
                const float h1n = (1.f - z) * n + z * hl1[jg];
                ring_st(ring1 + (size_t)(u & 7) * Hh + jg, pk(h1n, (u32)(u + 1)));
                resl = sigm(resl + h1n);
                if (u == T - 1) { outp[jg] = resl; outp[2 * Hh + jg] = h1n; }
            }
        }
    }
}

// ---------------------------------------------------------------- host
extern "C" void kernel_launch(void* const* d_in, const int* in_sizes, int n_in,
                              void* d_out, int out_size, void* d_ws, size_t ws_size,
                              hipStream_t stream)
{
    const float* input    = (const float*)d_in[0];
    const float* residual = (const float*)d_in[1];
    const float* memory   = (const float*)d_in[2];
    const float* Wproc    = (const float*)d_in[3];
    const float* bproc    = (const float*)d_in[4];
    const float* Wih0     = (const float*)d_in[5];
    const float* Whh0     = (const float*)d_in[6];
    const float* bih0     = (const float*)d_in[7];
    const float* bhh0     = (const float*)d_in[8];
    const float* Wih1     = (const float*)d_in[9];
    const float* Whh1     = (const float*)d_in[10];
    const float* bih1     = (const float*)d_in[11];
    const float* bhh1     = (const float*)d_in[12];
    const int L = in_sizes[0];
    const int T = L - 1;
    float* out = (float*)d_out;
    char* ws = (char*)d_ws;

    float* A     = (float*)(ws + WS_A);
    float* CC    = (float*)(ws + WS_CC);
    ull*   ring0 = (ull*)(ws + WS_RING0);
    ull*   ring1 = (ull*)(ws + WS_RING1);

    prep<<<dim3((TH + 255) / 256), dim3(256), 0, stream>>>(Wih0, Wproc, bproc, bih0, bhh0, A, CC);
    ringinit<<<dim3(1), dim3(512), 0, stream>>>(memory, ring0, ring1);
    fused<<<dim3(192), dim3(256), 0, stream>>>(input, residual, Whh0, bhh0, A, CC,
                                               Wih1, Whh1, bih1, bhh1,
                                               ring0, ring1, out, T);
}